// Round 7
// baseline (111.144 us; speedup 1.0000x reference)
//
#include <hip/hip_runtime.h>
#include <hip/hip_bf16.h>
#include <math.h>

// Problem constants (from reference)
#define B_   64
#define C_   256
#define H_   56
#define W_   56
#define L_   8
#define OUT_ 4096
#define KDIM 2048

#define NROI_BLOCKS 512
#define NGEMM_BLOCKS 256

typedef __attribute__((ext_vector_type(8))) short short8v;   // 8 bf16 (4 VGPRs)
typedef __attribute__((ext_vector_type(4))) float float4v;   // MFMA C/D

// 8-byte value with only 4-byte alignment guarantee (x0 can be odd).
struct __attribute__((packed, aligned(4))) F2 { float x, y; };

// fp32 -> bf16 bits, RNE
__device__ __forceinline__ unsigned short f2bf(float f) {
    unsigned u = __builtin_bit_cast(unsigned, f);
    return (unsigned short)((u + 0x7fffu + ((u >> 16) & 1u)) >> 16);
}

// ---------------------------------------------------------------------------
// Block-specialized fused kernel (NO grid barrier, NO cooperative launch).
// Grid = 768 blocks x 512 thr, all co-resident by construction:
//   waves 768*8=6144 <= 8192; LDS 32KB*3 <= 160KB; VGPR <= 85 (bounds 512,6).
// bid <  256: GEMM block. Pre-gate: prefetch its 16x2048 W tile -> bf16 in
//             32 VGPRs (coalesced, A-independent). Gate: spin until all 512
//             ROI blocks arrived (acquire/agent). Post: MFMA from regs,
//             A from pooled (global, L2-shared), LDS k-reduce + bias + relu.
// bid >= 256: ROI block (R4 structure): 1 roi, 512 thr = (c, iy), 4 packed
//             8B loads, bilinear+max, shfl_xor(1), store pooled bf16, then
//             t0: threadfence + atomicAdd(bar, RELEASE, AGENT). Never waits.
// ---------------------------------------------------------------------------
__global__ __launch_bounds__(512, 6) void fused_kernel(
    const float* __restrict__ feat,          // (64,256,56,56)
    const float* __restrict__ lms,           // (64,16)
    const float* __restrict__ Wl,            // (4096,2048) fp32
    const float* __restrict__ bl,            // (4096)
    unsigned short* __restrict__ pooled,     // ws: (64,2048) bf16 bits
    unsigned int* __restrict__ bar,          // ws: arrival counter (zeroed)
    float* __restrict__ out)                 // (64,4096) fp32
{
    __shared__ float red[8][64][16];   // 32 KB (GEMM blocks only)

    const int t   = threadIdx.x;
    const int bid = blockIdx.x;

    if (bid < NGEMM_BLOCKS) {
        // ================= GEMM block =================
        const int n0   = bid * 16;
        const int lane = t & 63;
        const int wv   = t >> 6;            // k-eighth 0..7
        const int rs   = lane & 15;         // W row / A row within fragment
        const int oct  = lane >> 4;         // k-octet (8 contiguous k)
        const int kq0  = wv * (KDIM / 8);   // 256 k per wave

        // ---- Pre-gate: prefetch W tile (A-independent, overlaps scatter).
        // Per lane: 8 k-steps x 8 contiguous fp32 -> bf16. Wave covers
        // 16 rows x 128B contiguous per step: perfect 64B-line utilization.
        const float* wrow = Wl + (size_t)(n0 + rs) * KDIM;
        short8v wbf[8];
        #pragma unroll
        for (int ks = 0; ks < 8; ++ks) {
            const int koff = kq0 + ks * 32 + oct * 8;
            const float4 w0 = *(const float4*)(wrow + koff);
            const float4 w1 = *(const float4*)(wrow + koff + 4);
            short8v v;
            v[0] = __builtin_bit_cast(short, (__bf16)w0.x);
            v[1] = __builtin_bit_cast(short, (__bf16)w0.y);
            v[2] = __builtin_bit_cast(short, (__bf16)w0.z);
            v[3] = __builtin_bit_cast(short, (__bf16)w0.w);
            v[4] = __builtin_bit_cast(short, (__bf16)w1.x);
            v[5] = __builtin_bit_cast(short, (__bf16)w1.y);
            v[6] = __builtin_bit_cast(short, (__bf16)w1.z);
            v[7] = __builtin_bit_cast(short, (__bf16)w1.w);
            wbf[ks] = v;
        }

        // ---- Gate: wait for all 512 ROI blocks (bounded spin for safety).
        if (t == 0) {
            unsigned v; int guard = 0;
            do {
                __builtin_amdgcn_s_sleep(8);
                v = __hip_atomic_load(bar, __ATOMIC_ACQUIRE,
                                      __HIP_MEMORY_SCOPE_AGENT);
            } while (v < (unsigned)NROI_BLOCKS && ++guard < (1 << 22));
        }
        __syncthreads();

        // ---- MFMA: A from pooled (global, L2-resident per XCD).
        float4v acc[4];
        #pragma unroll
        for (int mt = 0; mt < 4; ++mt) acc[mt] = (float4v){0.f, 0.f, 0.f, 0.f};

        #pragma unroll
        for (int ks = 0; ks < 8; ++ks) {
            const int koff = kq0 + ks * 32 + oct * 8;
            #pragma unroll
            for (int mt = 0; mt < 4; ++mt) {
                const short8v afrag = *(const short8v*)
                    ((const short*)pooled + (size_t)(mt * 16 + rs) * KDIM + koff);
                acc[mt] = __builtin_amdgcn_mfma_f32_16x16x32_bf16(
                    afrag, wbf[ks], acc[mt], 0, 0, 0);
            }
        }

        // ---- k-reduce across 8 waves, bias, relu, store.
        // C/D layout: col(n) = lane&15, row-within-16 = oct*4 + reg
        #pragma unroll
        for (int mt = 0; mt < 4; ++mt)
            #pragma unroll
            for (int r = 0; r < 4; ++r)
                red[wv][mt * 16 + oct * 4 + r][rs] = acc[mt][r];
        __syncthreads();

        #pragma unroll
        for (int i = 0; i < 2; ++i) {
            const int idx = t + i * 512;
            const int m = idx >> 4;
            const int n = idx & 15;
            float s = 0.0f;
            #pragma unroll
            for (int q = 0; q < 8; ++q) s += red[q][m][n];
            s += bl[n0 + n];
            out[(size_t)m * OUT_ + n0 + n] = s > 0.0f ? s : 0.0f;
        }
    } else {
        // ================= ROI block =================
        const int rblk = bid - NGEMM_BLOCKS;             // 0..511
        // XCD affinity: bid%8 == rblk%8 -> all 8 landmarks of a batch share
        // an XCD's L2 (row dedupe).
        const int xcd  = rblk & 7;
        const int idx  = rblk >> 3;                      // 0..63
        const int work = xcd * 64 + idx;                 // 0..511
        const int b = work >> 3;
        const int l = work & 7;
        const int c  = t >> 1;                           // 0..255
        const int iy = t & 1;                            // y sample (0/1)

        const float lx = lms[b * (L_ * 2) + 2 * l];
        const float ly = lms[b * (L_ * 2) + 2 * l + 1];
        const float tx = -1.0f + lx * (1.0f / 112.0f);
        const float ty = -1.0f + ly * (1.0f / 112.0f);
        const float Aaff = 2.0f / 7.0f;

        float wx[2]; int xb[2]; bool xhi[2];
        #pragma unroll
        for (int j = 0; j < 2; ++j) {
            const float base = (j == 0) ? -0.5f : 0.5f;
            const float gx = Aaff * base + tx;
            float fx = ((gx + 1.0f) * (float)W_ - 1.0f) * 0.5f;
            fx = fminf(fmaxf(fx, 0.0f), (float)(W_ - 1));
            const float fx0 = floorf(fx);
            wx[j] = fx - fx0;
            const int x0 = (int)fx0;
            xhi[j] = (x0 == W_ - 1);          // clamped: wx==0
            xb[j]  = xhi[j] ? (W_ - 2) : x0;  // packed 8B load base, in-row
        }
        float wyv; int y0v, y1v;
        {
            const float base = (iy == 0) ? -0.5f : 0.5f;
            const float gy = Aaff * base + ty;
            float fy = ((gy + 1.0f) * (float)H_ - 1.0f) * 0.5f;
            fy = fminf(fmaxf(fy, 0.0f), (float)(H_ - 1));
            const float fy0 = floorf(fy);
            wyv = fy - fy0;
            y0v = (int)fy0;
            y1v = min(y0v + 1, H_ - 1);
        }

        const float* fb = feat + ((size_t)(b * C_ + c)) * (H_ * W_);
        const float* r0 = fb + y0v * W_;
        const float* r1 = fb + y1v * W_;
        const F2 p00 = *(const F2*)(r0 + xb[0]);
        const F2 p01 = *(const F2*)(r0 + xb[1]);
        const F2 p10 = *(const F2*)(r1 + xb[0]);
        const F2 p11 = *(const F2*)(r1 + xb[1]);

        float mx;
        {
            const float v00 = xhi[0] ? p00.y : p00.x;
            const float v10 = xhi[0] ? p10.y : p10.x;
            const float top = v00 + wx[0] * (p00.y - v00);
            const float bot = v10 + wx[0] * (p10.y - v10);
            mx = top + wyv * (bot - top);
        }
        {
            const float v00 = xhi[1] ? p01.y : p01.x;
            const float v10 = xhi[1] ? p11.y : p11.x;
            const float top = v00 + wx[1] * (p01.y - v00);
            const float bot = v10 + wx[1] * (p11.y - v10);
            const float val = top + wyv * (bot - top);
            mx = fmaxf(mx, val);
        }
        mx = fmaxf(mx, __shfl_xor(mx, 1));
        if (iy == 0)
            pooled[(size_t)(b * L_ + l) * C_ + c] = f2bf(mx);

        // Arrive: make pooled visible device-wide, then bump the counter.
        __syncthreads();
        if (t == 0) {
            __threadfence();
            __hip_atomic_fetch_add(bar, 1u, __ATOMIC_RELEASE,
                                   __HIP_MEMORY_SCOPE_AGENT);
        }
    }
}

// ---------------------------------------------------------------------------
extern "C" void kernel_launch(void* const* d_in, const int* in_sizes, int n_in,
                              void* d_out, int out_size, void* d_ws, size_t ws_size,
                              hipStream_t stream) {
    const float* features  = (const float*)d_in[0];  // (64,256,56,56)
    const float* landmarks = (const float*)d_in[1];  // (64,16)
    const float* W_lin     = (const float*)d_in[2];  // (4096,2048)
    const float* b_lin     = (const float*)d_in[3];  // (4096,)
    float* out = (float*)d_out;                      // (64,4096)

    unsigned short* pooled = (unsigned short*)d_ws;                  // 256 KB
    unsigned int*   bar    = (unsigned int*)((char*)d_ws + 262144);  // counter

    hipMemsetAsync(bar, 0, sizeof(unsigned int), stream);
    fused_kernel<<<NGEMM_BLOCKS + NROI_BLOCKS, 512, 0, stream>>>(
        features, landmarks, W_lin, b_lin, pooled, bar, out);
}

// Round 8
// 36.429 us; speedup vs baseline: 3.0510x; 3.0510x over previous
//
#include <hip/hip_runtime.h>
#include <hip/hip_bf16.h>
#include <math.h>

// Problem constants (from reference)
#define B_   64
#define C_   256
#define H_   56
#define W_   56
#define L_   8
#define OUT_ 4096
#define KDIM 2048

typedef __attribute__((ext_vector_type(8))) short short8v;   // 8 bf16 (4 VGPRs)
typedef __attribute__((ext_vector_type(4))) float float4v;   // MFMA C/D

// 8-byte value with only 4-byte alignment guarantee (x0 can be odd).
struct __attribute__((packed, aligned(4))) F2 { float x, y; };

// fp32 -> bf16 bits, RNE
__device__ __forceinline__ unsigned short f2bf(float f) {
    unsigned u = __builtin_bit_cast(unsigned, f);
    return (unsigned short)((u + 0x7fffu + ((u >> 16) & 1u)) >> 16);
}

// ---------------------------------------------------------------------------
// Kernel 1: ROI gather + (optionally) W fp32->bf16 conversion, fused in one
// block so the BW-heavy W stream overlaps the latency-bound scatter.
// 512 blocks x 512 thr:
//   threads 0..255  (waves 0-3): one ROI per block, 1 thread/channel,
//       8 independent packed 8B loads (4 rows x 2 x-windows), bilinear,
//       max over the 2x2 grid, store pooled bf16. 8 waves/CU x 8 loads
//       = 64 outstanding lines/CU (same concurrency as R4).
//   threads 256..511 (waves 4-7, CONVW only): convert W rows
//       [bid*8, bid*8+8) fp32->bf16 into wbf (coalesced 32B/thread/iter).
// XCD affinity: bid&7 -> all 8 landmarks of a batch share one XCD's L2.
// ---------------------------------------------------------------------------
template<bool CONVW>
__global__ __launch_bounds__(512) void roi_convw_kernel(
    const float* __restrict__ feat,          // (64,256,56,56)
    const float* __restrict__ lms,           // (64,16)
    const float* __restrict__ Wl,            // (4096,2048) fp32
    unsigned short* __restrict__ pooled,     // ws: (64,2048) bf16 bits
    unsigned short* __restrict__ wbf)        // ws: (4096,2048) bf16 bits
{
    const int t   = threadIdx.x;
    const int bid = blockIdx.x;

    if (t < 256) {
        // ---------------- ROI half ----------------
        const int xcd  = bid & 7;
        const int idx  = bid >> 3;            // 0..63
        const int work = xcd * 64 + idx;      // roi id 0..511
        const int b = work >> 3;
        const int l = work & 7;
        const int c = t;                      // channel 0..255

        const float lx = lms[b * (L_ * 2) + 2 * l];
        const float ly = lms[b * (L_ * 2) + 2 * l + 1];
        const float tx = -1.0f + lx * (1.0f / 112.0f);
        const float ty = -1.0f + ly * (1.0f / 112.0f);
        const float Aaff = 2.0f / 7.0f;

        float wx[2]; int xb[2]; bool xhi[2];
        #pragma unroll
        for (int j = 0; j < 2; ++j) {
            const float base = (j == 0) ? -0.5f : 0.5f;
            const float gx = Aaff * base + tx;
            float fx = ((gx + 1.0f) * (float)W_ - 1.0f) * 0.5f;
            fx = fminf(fmaxf(fx, 0.0f), (float)(W_ - 1));
            const float fx0 = floorf(fx);
            wx[j] = fx - fx0;
            const int x0 = (int)fx0;
            xhi[j] = (x0 == W_ - 1);          // clamped: wx==0
            xb[j]  = xhi[j] ? (W_ - 2) : x0;  // packed 8B load base, in-row
        }
        float wy[2]; int y0[2], y1[2];
        #pragma unroll
        for (int i = 0; i < 2; ++i) {
            const float base = (i == 0) ? -0.5f : 0.5f;
            const float gy = Aaff * base + ty;
            float fy = ((gy + 1.0f) * (float)H_ - 1.0f) * 0.5f;
            fy = fminf(fmaxf(fy, 0.0f), (float)(H_ - 1));
            const float fy0 = floorf(fy);
            wy[i] = fy - fy0;
            y0[i] = (int)fy0;
            y1[i] = min(y0[i] + 1, H_ - 1);
        }

        const float* fb = feat + ((size_t)(b * C_ + c)) * (H_ * W_);
        // 8 independent packed loads: [ysample][row01][xwin]
        F2 p[2][2][2];
        #pragma unroll
        for (int i = 0; i < 2; ++i) {
            const float* r0 = fb + y0[i] * W_;
            const float* r1 = fb + y1[i] * W_;
            #pragma unroll
            for (int j = 0; j < 2; ++j) {
                p[i][0][j] = *(const F2*)(r0 + xb[j]);
                p[i][1][j] = *(const F2*)(r1 + xb[j]);
            }
        }
        float mx = -INFINITY;
        #pragma unroll
        for (int i = 0; i < 2; ++i) {
            #pragma unroll
            for (int j = 0; j < 2; ++j) {
                const float v00 = xhi[j] ? p[i][0][j].y : p[i][0][j].x;
                const float v10 = xhi[j] ? p[i][1][j].y : p[i][1][j].x;
                const float top = v00 + wx[j] * (p[i][0][j].y - v00);
                const float bot = v10 + wx[j] * (p[i][1][j].y - v10);
                const float val = top + wy[i] * (bot - top);
                mx = fmaxf(mx, val);
            }
        }
        pooled[(size_t)work * C_ + c] = f2bf(mx);
    } else if (CONVW) {
        // ---------------- W-convert half ----------------
        const int ti      = t - 256;          // 0..255
        const int rowbase = bid * 8;          // 8 W rows per block
        #pragma unroll
        for (int it = 0; it < 8; ++it) {
            const int g   = it * 256 + ti;    // 0..2047 (32B chunk id)
            const int row = g >> 8;           // 0..7
            const int ch8 = g & 255;          // 8-float group within row
            const float* src = Wl + (size_t)(rowbase + row) * KDIM + ch8 * 8;
            const float4 a  = *(const float4*)src;
            const float4 b4 = *(const float4*)(src + 4);
            short8v v;
            v[0] = __builtin_bit_cast(short, (__bf16)a.x);
            v[1] = __builtin_bit_cast(short, (__bf16)a.y);
            v[2] = __builtin_bit_cast(short, (__bf16)a.z);
            v[3] = __builtin_bit_cast(short, (__bf16)a.w);
            v[4] = __builtin_bit_cast(short, (__bf16)b4.x);
            v[5] = __builtin_bit_cast(short, (__bf16)b4.y);
            v[6] = __builtin_bit_cast(short, (__bf16)b4.z);
            v[7] = __builtin_bit_cast(short, (__bf16)b4.w);
            *(short8v*)&wbf[(size_t)(rowbase + row) * KDIM + ch8 * 8] = v;
        }
    }
}

// ---------------------------------------------------------------------------
// Kernel 2a: GEMM from pre-converted bf16 W (16.75 MB, one pass).
// 256 blocks x 512 thr (8 waves); tile M=64 x N=16; waves split K 8 ways;
// LDS k-reduce + bias + relu. A (pooled, 256 KB) is L2/L3-resident.
// ---------------------------------------------------------------------------
__global__ __launch_bounds__(512) void gemm_bf16_kernel(
    const unsigned short* __restrict__ Abf,  // (64,2048) bf16
    const unsigned short* __restrict__ Wbf,  // (4096,2048) bf16
    const float* __restrict__ bl,            // (4096)
    float* __restrict__ out)                 // (64,4096) fp32
{
    __shared__ float red[8][64][16];   // 32 KB

    const int t    = threadIdx.x;
    const int lane = t & 63;
    const int wv   = t >> 6;            // k-eighth 0..7
    const int n0   = blockIdx.x * 16;
    const int rs   = lane & 15;         // W row / A row within fragment
    const int oct  = lane >> 4;         // k-octet (8 contiguous k)
    const int kq0  = wv * (KDIM / 8);   // 256 k per wave

    float4v acc[4];
    #pragma unroll
    for (int mt = 0; mt < 4; ++mt) acc[mt] = (float4v){0.f, 0.f, 0.f, 0.f};

    const short* wrow = (const short*)Wbf + (size_t)(n0 + rs) * KDIM;

    #pragma unroll 4
    for (int ks = 0; ks < 8; ++ks) {
        const int koff = kq0 + ks * 32 + oct * 8;
        const short8v bfrag = *(const short8v*)(wrow + koff);
        #pragma unroll
        for (int mt = 0; mt < 4; ++mt) {
            const short8v afrag = *(const short8v*)
                ((const short*)Abf + (size_t)(mt * 16 + rs) * KDIM + koff);
            acc[mt] = __builtin_amdgcn_mfma_f32_16x16x32_bf16(
                afrag, bfrag, acc[mt], 0, 0, 0);
        }
    }

    // C/D layout: col(n) = lane&15, row-within-16 = oct*4 + reg
    #pragma unroll
    for (int mt = 0; mt < 4; ++mt)
        #pragma unroll
        for (int r = 0; r < 4; ++r)
            red[wv][mt * 16 + oct * 4 + r][rs] = acc[mt][r];
    __syncthreads();

    #pragma unroll
    for (int i = 0; i < 2; ++i) {
        const int idx = t + i * 512;
        const int m = idx >> 4;
        const int n = idx & 15;
        float s = 0.0f;
        #pragma unroll
        for (int q = 0; q < 8; ++q) s += red[q][m][n];
        s += bl[n0 + n];
        out[(size_t)m * OUT_ + n0 + n] = s > 0.0f ? s : 0.0f;
    }
}

// ---------------------------------------------------------------------------
// Kernel 2b (fallback if ws too small for the W copy): GEMM reading fp32 W
// directly, converting in-register (R4 structure).
// ---------------------------------------------------------------------------
__global__ __launch_bounds__(512) void gemm_f32w_kernel(
    const unsigned short* __restrict__ Abf,  // (64,2048) bf16
    const float* __restrict__ Wl,            // (4096,2048) fp32
    const float* __restrict__ bl,            // (4096)
    float* __restrict__ out)                 // (64,4096) fp32
{
    __shared__ float red[8][64][16];

    const int t    = threadIdx.x;
    const int lane = t & 63;
    const int wv   = t >> 6;
    const int n0   = blockIdx.x * 16;
    const int rs   = lane & 15;
    const int oct  = lane >> 4;
    const int kq0  = wv * (KDIM / 8);

    float4v acc[4];
    #pragma unroll
    for (int mt = 0; mt < 4; ++mt) acc[mt] = (float4v){0.f, 0.f, 0.f, 0.f};

    const float* wrow = Wl + (size_t)(n0 + rs) * KDIM;

    #pragma unroll 4
    for (int ks = 0; ks < 8; ++ks) {
        const int koff = kq0 + ks * 32 + oct * 8;
        const float4 w0 = *(const float4*)(wrow + koff);
        const float4 w1 = *(const float4*)(wrow + koff + 4);
        short8v bfrag;
        bfrag[0] = __builtin_bit_cast(short, (__bf16)w0.x);
        bfrag[1] = __builtin_bit_cast(short, (__bf16)w0.y);
        bfrag[2] = __builtin_bit_cast(short, (__bf16)w0.z);
        bfrag[3] = __builtin_bit_cast(short, (__bf16)w0.w);
        bfrag[4] = __builtin_bit_cast(short, (__bf16)w1.x);
        bfrag[5] = __builtin_bit_cast(short, (__bf16)w1.y);
        bfrag[6] = __builtin_bit_cast(short, (__bf16)w1.z);
        bfrag[7] = __builtin_bit_cast(short, (__bf16)w1.w);
        #pragma unroll
        for (int mt = 0; mt < 4; ++mt) {
            const short8v afrag = *(const short8v*)
                ((const short*)Abf + (size_t)(mt * 16 + rs) * KDIM + koff);
            acc[mt] = __builtin_amdgcn_mfma_f32_16x16x32_bf16(
                afrag, bfrag, acc[mt], 0, 0, 0);
        }
    }

    #pragma unroll
    for (int mt = 0; mt < 4; ++mt)
        #pragma unroll
        for (int r = 0; r < 4; ++r)
            red[wv][mt * 16 + oct * 4 + r][rs] = acc[mt][r];
    __syncthreads();

    #pragma unroll
    for (int i = 0; i < 2; ++i) {
        const int idx = t + i * 512;
        const int m = idx >> 4;
        const int n = idx & 15;
        float s = 0.0f;
        #pragma unroll
        for (int q = 0; q < 8; ++q) s += red[q][m][n];
        s += bl[n0 + n];
        out[(size_t)m * OUT_ + n0 + n] = s > 0.0f ? s : 0.0f;
    }
}

// ---------------------------------------------------------------------------
extern "C" void kernel_launch(void* const* d_in, const int* in_sizes, int n_in,
                              void* d_out, int out_size, void* d_ws, size_t ws_size,
                              hipStream_t stream) {
    const float* features  = (const float*)d_in[0];  // (64,256,56,56)
    const float* landmarks = (const float*)d_in[1];  // (64,16)
    const float* W_lin     = (const float*)d_in[2];  // (4096,2048)
    const float* b_lin     = (const float*)d_in[3];  // (4096,)
    float* out = (float*)d_out;                      // (64,4096)

    unsigned short* pooled = (unsigned short*)d_ws;                 // 256 KB
    unsigned short* wbf    = (unsigned short*)((char*)d_ws + 262144);

    const size_t need = 262144 + (size_t)OUT_ * KDIM * 2;           // ~17 MB
    if (ws_size >= need) {
        roi_convw_kernel<true><<<512, 512, 0, stream>>>(
            features, landmarks, W_lin, pooled, wbf);
        gemm_bf16_kernel<<<OUT_ / 16, 512, 0, stream>>>(
            pooled, wbf, b_lin, out);
    } else {
        roi_convw_kernel<false><<<512, 512, 0, stream>>>(
            features, landmarks, W_lin, pooled, nullptr);
        gemm_f32w_kernel<<<OUT_ / 16, 512, 0, stream>>>(
            pooled, W_lin, b_lin, out);
    }
}

// Round 9
// 30.157 us; speedup vs baseline: 3.6855x; 1.2080x over previous
//
#include <hip/hip_runtime.h>
#include <hip/hip_bf16.h>
#include <math.h>

// Problem constants (from reference)
#define B_   64
#define C_   256
#define H_   56
#define W_   56
#define L_   8
#define OUT_ 4096
#define KDIM 2048

typedef __attribute__((ext_vector_type(8))) short short8v;   // 8 bf16 (4 VGPRs)
typedef __attribute__((ext_vector_type(4))) float float4v;   // MFMA C/D

// 8-byte value with only 4-byte alignment guarantee (x0 can be odd).
struct __attribute__((packed, aligned(4))) F2 { float x, y; };

// fp32 -> bf16 bits, RNE
__device__ __forceinline__ unsigned short f2bf(float f) {
    unsigned u = __builtin_bit_cast(unsigned, f);
    return (unsigned short)((u + 0x7fffu + ((u >> 16) & 1u)) >> 16);
}

// ---------------------------------------------------------------------------
// Kernel 1: RoI gather restructured for HBM row-buffer locality.
// One WAVE = one (batch, channel) slab (12.5 KB). Lane = (l, iy, r01, jx):
//   jx  = lane&1      : x-window of the 2x2 grid
//   r01 = (lane>>1)&1 : bottom/top row of the bilinear pair
//   iy  = (lane>>2)&1 : y-sample of the 2x2 grid
//   l   = lane>>3     : landmark (roi) 0..7
// Each thread: ONE packed 8B load; all 64 addresses of the wave fall in one
// 12.5 KB slab (~6 HBM pages) -> row-buffer hits instead of random misses.
// Bilinear+max via shuffles: v = wr*lerp_x; sum r01 (xor2); max jx (xor1);
// max iy (xor4). Lane l*8 writes pooled[(b*8+l)*256 + c].
// Grid = 64 batches x 64 cgroups = 4096 blocks x 256 thr (4 waves = 4 ch).
// ---------------------------------------------------------------------------
__global__ __launch_bounds__(256) void roi_pool_kernel(
    const float* __restrict__ feat,      // (64,256,56,56)
    const float* __restrict__ lms,       // (64,16)
    unsigned short* __restrict__ pooled) // (64,2048) bf16 bits
{
    const int bid  = blockIdx.x;
    const int b    = bid >> 6;           // batch 0..63
    const int cg   = bid & 63;           // channel group 0..63
    const int t    = threadIdx.x;
    const int wv   = t >> 6;             // wave 0..3
    const int lane = t & 63;
    const int c    = cg * 4 + wv;        // channel 0..255

    const int jx  = lane & 1;
    const int r01 = (lane >> 1) & 1;
    const int iy  = (lane >> 2) & 1;
    const int l   = lane >> 3;

    // landmark (8B aligned float2)
    const float2 lm = *(const float2*)(lms + b * (L_ * 2) + 2 * l);
    const float tx = -1.0f + lm.x * (1.0f / 112.0f);
    const float ty = -1.0f + lm.y * (1.0f / 112.0f);
    const float Aaff = 2.0f / 7.0f;

    // x window for this lane's jx
    const float bx = jx ? 0.5f : -0.5f;
    float fx = ((Aaff * bx + tx + 1.0f) * (float)W_ - 1.0f) * 0.5f;
    fx = fminf(fmaxf(fx, 0.0f), (float)(W_ - 1));
    const float fx0 = floorf(fx);
    const float wx = fx - fx0;
    const int x0 = (int)fx0;
    const bool xhi = (x0 == W_ - 1);     // clamped: wx == 0
    const int xb = xhi ? (W_ - 2) : x0;  // packed 8B load base, in-row

    // y sample + row select for this lane's (iy, r01)
    const float by = iy ? 0.5f : -0.5f;
    float fy = ((Aaff * by + ty + 1.0f) * (float)H_ - 1.0f) * 0.5f;
    fy = fminf(fmaxf(fy, 0.0f), (float)(H_ - 1));
    const float fy0 = floorf(fy);
    const float wy = fy - fy0;
    const int y0 = (int)fy0;
    const int row = r01 ? min(y0 + 1, H_ - 1) : y0;
    const float wr = r01 ? wy : (1.0f - wy);

    // the one gather: 8B inside this wave's (b,c) slab
    const float* fb = feat + ((size_t)(b * C_ + c)) * (H_ * W_) + row * W_ + xb;
    const F2 p = *(const F2*)fb;

    const float v0 = xhi ? p.y : p.x;          // row[x0] (border clamp)
    const float lerpx = v0 + wx * (p.y - v0);  // row[x0] + wx*(row[x1]-row[x0])
    float v = wr * lerpx;

    v += __shfl_xor(v, 2);               // sum bilinear row pair (r01)
    v = fmaxf(v, __shfl_xor(v, 1));      // max over x-windows (jx)
    v = fmaxf(v, __shfl_xor(v, 4));      // max over y-samples (iy)

    if ((lane & 7) == 0)
        pooled[(size_t)(b * L_ + l) * C_ + c] = f2bf(v);
}

// ---------------------------------------------------------------------------
// Kernel 2: out = relu(A @ W^T + b) via bf16 MFMA (R4 structure, proven).
// A: pooled bf16 (64x2048, L2-resident). W: fp32 (4096x2048), streamed from
// HBM once, converted in-register (v_cvt_pk_bf16_f32 via __bf16 casts).
// 256 blocks x 512 thr (8 waves); tile M=64 x N=16; waves split K 8 ways;
// LDS k-reduce + bias + relu.
// ---------------------------------------------------------------------------
__global__ __launch_bounds__(512) void gemm_mfma_kernel(
    const unsigned short* __restrict__ Abf,  // (64,2048) bf16
    const float* __restrict__ Wl,            // (4096,2048) fp32
    const float* __restrict__ bl,            // (4096)
    float* __restrict__ out)                 // (64,4096) fp32
{
    __shared__ float red[8][64][16];   // 32 KB

    const int t    = threadIdx.x;
    const int lane = t & 63;
    const int wv   = t >> 6;            // k-eighth 0..7
    const int n0   = blockIdx.x * 16;
    const int rs   = lane & 15;         // W row / A row within fragment
    const int oct  = lane >> 4;         // k-octet (8 contiguous k)
    const int kq0  = wv * (KDIM / 8);   // 256 k per wave

    float4v acc[4];
    #pragma unroll
    for (int mt = 0; mt < 4; ++mt) acc[mt] = (float4v){0.f, 0.f, 0.f, 0.f};

    const float* wrow = Wl + (size_t)(n0 + rs) * KDIM;

    #pragma unroll 4
    for (int ks = 0; ks < 8; ++ks) {
        const int koff = kq0 + ks * 32 + oct * 8;
        const float4 w0 = *(const float4*)(wrow + koff);
        const float4 w1 = *(const float4*)(wrow + koff + 4);
        short8v bfrag;
        bfrag[0] = __builtin_bit_cast(short, (__bf16)w0.x);
        bfrag[1] = __builtin_bit_cast(short, (__bf16)w0.y);
        bfrag[2] = __builtin_bit_cast(short, (__bf16)w0.z);
        bfrag[3] = __builtin_bit_cast(short, (__bf16)w0.w);
        bfrag[4] = __builtin_bit_cast(short, (__bf16)w1.x);
        bfrag[5] = __builtin_bit_cast(short, (__bf16)w1.y);
        bfrag[6] = __builtin_bit_cast(short, (__bf16)w1.z);
        bfrag[7] = __builtin_bit_cast(short, (__bf16)w1.w);
        #pragma unroll
        for (int mt = 0; mt < 4; ++mt) {
            const short8v afrag = *(const short8v*)
                ((const short*)Abf + (size_t)(mt * 16 + rs) * KDIM + koff);
            acc[mt] = __builtin_amdgcn_mfma_f32_16x16x32_bf16(
                afrag, bfrag, acc[mt], 0, 0, 0);
        }
    }

    // C/D layout: col(n) = lane&15, row-within-16 = oct*4 + reg
    #pragma unroll
    for (int mt = 0; mt < 4; ++mt)
        #pragma unroll
        for (int r = 0; r < 4; ++r)
            red[wv][mt * 16 + oct * 4 + r][rs] = acc[mt][r];
    __syncthreads();

    #pragma unroll
    for (int i = 0; i < 2; ++i) {
        const int idx = t + i * 512;
        const int m = idx >> 4;
        const int n = idx & 15;
        float s = 0.0f;
        #pragma unroll
        for (int q = 0; q < 8; ++q) s += red[q][m][n];
        s += bl[n0 + n];
        out[(size_t)m * OUT_ + n0 + n] = s > 0.0f ? s : 0.0f;
    }
}

// ---------------------------------------------------------------------------
extern "C" void kernel_launch(void* const* d_in, const int* in_sizes, int n_in,
                              void* d_out, int out_size, void* d_ws, size_t ws_size,
                              hipStream_t stream) {
    const float* features  = (const float*)d_in[0];  // (64,256,56,56)
    const float* landmarks = (const float*)d_in[1];  // (64,16)
    const float* W_lin     = (const float*)d_in[2];  // (4096,2048)
    const float* b_lin     = (const float*)d_in[3];  // (4096,)
    float* out = (float*)d_out;                      // (64,4096)

    unsigned short* pooled = (unsigned short*)d_ws;  // (64,2048) bf16 = 256 KB

    roi_pool_kernel<<<B_ * 64, 256, 0, stream>>>(features, landmarks, pooled);
    gemm_mfma_kernel<<<OUT_ / 16, 512, 0, stream>>>(pooled, W_lin, b_lin, out);
}

// Round 10
// 29.233 us; speedup vs baseline: 3.8021x; 1.0316x over previous
//
#include <hip/hip_runtime.h>
#include <hip/hip_bf16.h>
#include <math.h>

// Problem constants (from reference)
#define B_   64
#define C_   256
#define H_   56
#define W_   56
#define L_   8
#define OUT_ 4096
#define KDIM 2048

typedef __attribute__((ext_vector_type(8))) short short8v;   // 8 bf16 (4 VGPRs)
typedef __attribute__((ext_vector_type(4))) float float4v;   // MFMA C/D

// 8-byte value with only 4-byte alignment guarantee (x0 can be odd).
struct __attribute__((packed, aligned(4))) F2 { float x, y; };

// fp32 -> bf16 bits, RNE
__device__ __forceinline__ unsigned short f2bf(float f) {
    unsigned u = __builtin_bit_cast(unsigned, f);
    return (unsigned short)((u + 0x7fffu + ((u >> 16) & 1u)) >> 16);
}

// ---------------------------------------------------------------------------
// Kernel 1: RoI gather (R9 structure — empirically at the HBM-random floor).
// One WAVE = one (batch, channel) slab (12.5 KB). Lane = (l, iy, r01, jx).
// Each thread: ONE packed 8B load; bilinear+max via shuffles.
// Grid = 64 batches x 64 cgroups = 4096 blocks x 256 thr (4 waves = 4 ch).
// ---------------------------------------------------------------------------
__global__ __launch_bounds__(256) void roi_pool_kernel(
    const float* __restrict__ feat,      // (64,256,56,56)
    const float* __restrict__ lms,       // (64,16)
    unsigned short* __restrict__ pooled) // (64,2048) bf16 bits
{
    const int bid  = blockIdx.x;
    const int b    = bid >> 6;           // batch 0..63
    const int cg   = bid & 63;           // channel group 0..63
    const int t    = threadIdx.x;
    const int wv   = t >> 6;             // wave 0..3
    const int lane = t & 63;
    const int c    = cg * 4 + wv;        // channel 0..255

    const int jx  = lane & 1;
    const int r01 = (lane >> 1) & 1;
    const int iy  = (lane >> 2) & 1;
    const int l   = lane >> 3;

    // landmark (8B aligned float2)
    const float2 lm = *(const float2*)(lms + b * (L_ * 2) + 2 * l);
    const float tx = -1.0f + lm.x * (1.0f / 112.0f);
    const float ty = -1.0f + lm.y * (1.0f / 112.0f);
    const float Aaff = 2.0f / 7.0f;

    // x window for this lane's jx
    const float bx = jx ? 0.5f : -0.5f;
    float fx = ((Aaff * bx + tx + 1.0f) * (float)W_ - 1.0f) * 0.5f;
    fx = fminf(fmaxf(fx, 0.0f), (float)(W_ - 1));
    const float fx0 = floorf(fx);
    const float wx = fx - fx0;
    const int x0 = (int)fx0;
    const bool xhi = (x0 == W_ - 1);     // clamped: wx == 0
    const int xb = xhi ? (W_ - 2) : x0;  // packed 8B load base, in-row

    // y sample + row select for this lane's (iy, r01)
    const float by = iy ? 0.5f : -0.5f;
    float fy = ((Aaff * by + ty + 1.0f) * (float)H_ - 1.0f) * 0.5f;
    fy = fminf(fmaxf(fy, 0.0f), (float)(H_ - 1));
    const float fy0 = floorf(fy);
    const float wy = fy - fy0;
    const int y0 = (int)fy0;
    const int row = r01 ? min(y0 + 1, H_ - 1) : y0;
    const float wr = r01 ? wy : (1.0f - wy);

    // the one gather: 8B inside this wave's (b,c) slab
    const float* fb = feat + ((size_t)(b * C_ + c)) * (H_ * W_) + row * W_ + xb;
    const F2 p = *(const F2*)fb;

    const float v0 = xhi ? p.y : p.x;          // row[x0] (border clamp)
    const float lerpx = v0 + wx * (p.y - v0);  // row[x0] + wx*(row[x1]-row[x0])
    float v = wr * lerpx;

    v += __shfl_xor(v, 2);               // sum bilinear row pair (r01)
    v = fmaxf(v, __shfl_xor(v, 1));      // max over x-windows (jx)
    v = fmaxf(v, __shfl_xor(v, 4));      // max over y-samples (iy)

    if ((lane & 7) == 0)
        pooled[(size_t)(b * L_ + l) * C_ + c] = f2bf(v);
}

// ---------------------------------------------------------------------------
// Kernel 2: out = relu(A @ W^T + b) via bf16 MFMA, FULL W-strip prefetch.
// Each wave prefetches its entire 16-row x 32-k W strip (16 x dwordx4 =
// 64 VGPRs) before the MFMA loop -> all HBM loads in flight immediately
// (128 outstanding 16B loads/CU), then cvt+MFMA drains them.
// 256 blocks x 512 thr (8 waves); tile M=64 x N=16; waves split K 8 ways;
// LDS k-reduce + bias + relu. A (pooled, 256 KB) is L2/L3-resident.
// ---------------------------------------------------------------------------
__global__ __launch_bounds__(512) void gemm_mfma_kernel(
    const unsigned short* __restrict__ Abf,  // (64,2048) bf16
    const float* __restrict__ Wl,            // (4096,2048) fp32
    const float* __restrict__ bl,            // (4096)
    float* __restrict__ out)                 // (64,4096) fp32
{
    __shared__ float red[8][64][16];   // 32 KB

    const int t    = threadIdx.x;
    const int lane = t & 63;
    const int wv   = t >> 6;            // k-eighth 0..7
    const int n0   = blockIdx.x * 16;
    const int rs   = lane & 15;         // W row / A row within fragment
    const int oct  = lane >> 4;         // k-octet (8 contiguous k)
    const int kq0  = wv * (KDIM / 8);   // 256 k per wave

    const float* wrow = Wl + (size_t)(n0 + rs) * KDIM;

    // ---- Prefetch the wave's whole W strip: 16 independent dwordx4 loads.
    float4 wA[8], wB[8];                // 64 VGPRs
    #pragma unroll
    for (int ks = 0; ks < 8; ++ks) {
        const int koff = kq0 + ks * 32 + oct * 8;
        wA[ks] = *(const float4*)(wrow + koff);
        wB[ks] = *(const float4*)(wrow + koff + 4);
    }

    float4v acc[4];
    #pragma unroll
    for (int mt = 0; mt < 4; ++mt) acc[mt] = (float4v){0.f, 0.f, 0.f, 0.f};

    #pragma unroll
    for (int ks = 0; ks < 8; ++ks) {
        const int koff = kq0 + ks * 32 + oct * 8;
        const float4 w0 = wA[ks];
        const float4 w1 = wB[ks];
        short8v bfrag;
        bfrag[0] = __builtin_bit_cast(short, (__bf16)w0.x);
        bfrag[1] = __builtin_bit_cast(short, (__bf16)w0.y);
        bfrag[2] = __builtin_bit_cast(short, (__bf16)w0.z);
        bfrag[3] = __builtin_bit_cast(short, (__bf16)w0.w);
        bfrag[4] = __builtin_bit_cast(short, (__bf16)w1.x);
        bfrag[5] = __builtin_bit_cast(short, (__bf16)w1.y);
        bfrag[6] = __builtin_bit_cast(short, (__bf16)w1.z);
        bfrag[7] = __builtin_bit_cast(short, (__bf16)w1.w);
        #pragma unroll
        for (int mt = 0; mt < 4; ++mt) {
            const short8v afrag = *(const short8v*)
                ((const short*)Abf + (size_t)(mt * 16 + rs) * KDIM + koff);
            acc[mt] = __builtin_amdgcn_mfma_f32_16x16x32_bf16(
                afrag, bfrag, acc[mt], 0, 0, 0);
        }
    }

    // C/D layout: col(n) = lane&15, row-within-16 = oct*4 + reg
    #pragma unroll
    for (int mt = 0; mt < 4; ++mt)
        #pragma unroll
        for (int r = 0; r < 4; ++r)
            red[wv][mt * 16 + oct * 4 + r][rs] = acc[mt][r];
    __syncthreads();

    #pragma unroll
    for (int i = 0; i < 2; ++i) {
        const int idx = t + i * 512;
        const int m = idx >> 4;
        const int n = idx & 15;
        float s = 0.0f;
        #pragma unroll
        for (int q = 0; q < 8; ++q) s += red[q][m][n];
        s += bl[n0 + n];
        out[(size_t)m * OUT_ + n0 + n] = s > 0.0f ? s : 0.0f;
    }
}

// ---------------------------------------------------------------------------
extern "C" void kernel_launch(void* const* d_in, const int* in_sizes, int n_in,
                              void* d_out, int out_size, void* d_ws, size_t ws_size,
                              hipStream_t stream) {
    const float* features  = (const float*)d_in[0];  // (64,256,56,56)
    const float* landmarks = (const float*)d_in[1];  // (64,16)
    const float* W_lin     = (const float*)d_in[2];  // (4096,2048)
    const float* b_lin     = (const float*)d_in[3];  // (4096,)
    float* out = (float*)d_out;                      // (64,4096)

    unsigned short* pooled = (unsigned short*)d_ws;  // (64,2048) bf16 = 256 KB

    roi_pool_kernel<<<B_ * 64, 256, 0, stream>>>(features, landmarks, pooled);
    gemm_mfma_kernel<<<OUT_ / 16, 512, 0, stream>>>(pooled, W_lin, b_lin, out);
}